// Round 13
// baseline (230.549 us; speedup 1.0000x reference)
//
#include <hip/hip_runtime.h>
#include <hip/hip_bf16.h>

#define N_NODES 20000
#define MPAD    20096
#define E_EDGES 400000
#define LATENT 128
#define H1 256
#define HIDDEN 512
#define OUT_D 64
#define HEADS 4
#define NEG_SLOPE 0.2f
#define NBLK_SCAN ((N_NODES + 255) / 256)   // 79

typedef __attribute__((ext_vector_type(8))) __bf16 bf16x8;
typedef __attribute__((ext_vector_type(4))) float f32x4;
typedef __attribute__((ext_vector_type(4))) unsigned short u16x4;

__device__ __forceinline__ unsigned short f2bf(float f) {
    union { float f; unsigned int u; } v; v.f = f;
    unsigned int r = v.u + 0x7fffu + ((v.u >> 16) & 1u);  // RNE
    return (unsigned short)(r >> 16);
}
__device__ __forceinline__ float bf2f(unsigned short u) {
    union { unsigned int u; float f; } v; v.u = ((unsigned int)u) << 16;
    return v.f;
}

// async global->LDS DMA, 16B/lane: global addr is per-lane, LDS dest = base + lane*16.
// Crucially: has a side effect, so the compiler CANNOT sink it (unlike the register
// prefetches of R8-R11 which were all defeated).
__device__ __forceinline__ void gl_lds16(const unsigned short* g, unsigned short* l) {
    __builtin_amdgcn_global_load_lds(
        (const __attribute__((address_space(1))) unsigned int*)g,
        (__attribute__((address_space(3))) unsigned int*)l,
        16, 0, 0);
}

// ---------------- weights transpose-convert + degree histogram (ONE launch) ----------------
#define SEG1 (LATENT * H1)
#define SEG2 (H1 * HIDDEN)
#define SEG3 (HIDDEN * HEADS * OUT_D)
#define WTOT (SEG1 + SEG2 + SEG3)
__global__ __launch_bounds__(256)
void prep_kernel(const float* __restrict__ W1, const float* __restrict__ W2,
                 const float* __restrict__ Wg, const int* __restrict__ ei,
                 unsigned short* __restrict__ W1t, unsigned short* __restrict__ W2t,
                 unsigned short* __restrict__ Wgt, int* __restrict__ deg) {
    int t = blockIdx.x * blockDim.x + threadIdx.x;
    if (t < SEG1) { int k = t >> 8, n = t & 255; W1t[n * LATENT + k] = f2bf(W1[t]); return; }
    t -= SEG1;
    if (t < SEG2) { int k = t >> 9, n = t & 511; W2t[n * H1 + k] = f2bf(W2[t]); return; }
    t -= SEG2;
    if (t < SEG3) { int k = t >> 8, n = t & 255; Wgt[n * HIDDEN + k] = f2bf(Wg[t]); return; }
    t -= SEG3;
    if (t < E_EDGES) atomicAdd(&deg[ei[E_EDGES + t]], 1);
}

// ---------------- fused MLP v2: LDS-staged weights + row-split waves ----------------
// TM=64 rows, 314 blocks, 256 threads. Wave w owns rows w*16..+16 for ALL layers, so
// x1/x2 stay in registers (packed bf16) and every weight fragment is shared by all 4
// waves: staged once per block into LDS via async global_load_lds double-buffer
// (16 KB/chunk). A-fragments for layers 2/3 are rebuilt from the register-resident
// activations with 8 shuffles per kt. LDS = z 17.4 KB + 32 KB wbuf = 49.4 KB.
#define TMB 64
#define ZPITCH 136
__device__ __forceinline__ bf16x8 gather_afrag(const unsigned int* xr, int kt, int q, int fr) {
    // dest lane (fr,q) needs x[fr][kt*32 + q*8 .. +7]: frag nt = 2kt + (q>>1),
    // chunk a (cols (q&1)*8..+3) from lane (fr, 2(q&1)), chunk b (+4..+7) from +16.
    const int srcA = ((q & 1) << 1) * 16 + fr;
    const int srcB = srcA + 16;
    const int base = 4 * kt;   // dword index of frag 2kt (2 dwords per frag)
    unsigned int e0a = (unsigned int)__shfl((int)xr[base + 0], srcA, 64);
    unsigned int e1a = (unsigned int)__shfl((int)xr[base + 1], srcA, 64);
    unsigned int e0b = (unsigned int)__shfl((int)xr[base + 0], srcB, 64);
    unsigned int e1b = (unsigned int)__shfl((int)xr[base + 1], srcB, 64);
    unsigned int o0a = (unsigned int)__shfl((int)xr[base + 2], srcA, 64);
    unsigned int o1a = (unsigned int)__shfl((int)xr[base + 3], srcA, 64);
    unsigned int o0b = (unsigned int)__shfl((int)xr[base + 2], srcB, 64);
    unsigned int o1b = (unsigned int)__shfl((int)xr[base + 3], srcB, 64);
    const bool odd = (q >= 2);
    union { unsigned int u[4]; bf16x8 v; } r;
    r.u[0] = odd ? o0a : e0a;
    r.u[1] = odd ? o1a : e1a;
    r.u[2] = odd ? o0b : e0b;
    r.u[3] = odd ? o1b : e1b;
    return r.v;
}

__global__ __launch_bounds__(256)
void mlp_all_kernel(const float* __restrict__ z,
                    const unsigned short* __restrict__ W1t,
                    const unsigned short* __restrict__ W2t,
                    const unsigned short* __restrict__ Wgt,
                    const float* __restrict__ b1, const float* __restrict__ b2,
                    const float* __restrict__ att_src, const float* __restrict__ att_dst,
                    unsigned short* __restrict__ hb,
                    float* __restrict__ a_src, float* __restrict__ a_dst) {
    __shared__ unsigned short zbf[TMB * ZPITCH];     // 17.4 KB
    __shared__ unsigned short wbuf[2 * 16 * 512];    // 2 x 16 KB weight chunks
    const int tid = threadIdx.x;
    const int wave = tid >> 6, lane = tid & 63;
    const int m0 = blockIdx.x * TMB;
    const int fr = lane & 15, q = lane >> 4;
    const int row = m0 + wave * 16 + fr;             // this lane's private row

    // stage 4 frags (this wave's share of a 16-frag chunk) of Wt[N][K] for K-chunk kt
    auto stage_chunk = [&](const unsigned short* Wt, int K, int ntbase, int kt, int buf) {
#pragma unroll
        for (int i = 0; i < 4; i++) {
            const int f = (wave << 2) + i;
            gl_lds16(Wt + (size_t)((ntbase + f) * 16 + fr) * K + kt * 32 + q * 8,
                     wbuf + buf * 8192 + f * 512);
        }
    };
    auto ldw = [&](int buf, int f) -> bf16x8 {
        return *(const bf16x8*)(wbuf + buf * 8192 + f * 512 + lane * 8);
    };

    // issue layer-1 kt=0 weight DMA, then convert the z tile (overlaps the DMA)
    stage_chunk(W1t, LATENT, 0, 0, 0);
    {
        const int r = tid >> 2, c0 = (tid & 3) * 32;
        const int zrow = min(m0 + r, N_NODES - 1);
        const float* zp = z + (size_t)zrow * LATENT + c0;
#pragma unroll
        for (int i = 0; i < 8; i++) {
            f32x4 v = *(const f32x4*)(zp + i * 4);
            u16x4 p = { f2bf(v[0]), f2bf(v[1]), f2bf(v[2]), f2bf(v[3]) };
            *(u16x4*)(zbf + r * ZPITCH + c0 + i * 4) = p;
        }
    }
    __syncthreads();   // z ready + chunk(1,kt0) drained (barrier waits vmcnt)

    // ---- layer 1: K=128 (4 kt), each wave: its 16 rows x all 256 cols (16 frags) ----
    f32x4 acc1[16] = {};
#pragma unroll
    for (int kt = 0; kt < 4; kt++) {
        const int buf = kt & 1;
        if (kt < 3) stage_chunk(W1t, LATENT, 0, kt + 1, buf ^ 1);
        else        stage_chunk(W2t, H1, 0, 0, buf ^ 1);      // layer-2 nh0 kt0
        bf16x8 af = *(const bf16x8*)(zbf + (wave * 16 + fr) * ZPITCH + kt * 32 + q * 8);
#pragma unroll
        for (int f = 0; f < 16; f++)
            acc1[f] = __builtin_amdgcn_mfma_f32_16x16x32_bf16(ldw(buf, f), af, acc1[f], 0, 0, 0);
        __syncthreads();
    }

    // layer-1 epilogue: bias+relu -> packed bf16 in registers (x1 never touches memory)
    unsigned int x1r[32];
#pragma unroll
    for (int nt = 0; nt < 16; nt++) {
        const f32x4 bv = *(const f32x4*)(b1 + nt * 16 + q * 4);
        float v0 = fmaxf(acc1[nt][0] + bv[0], 0.f);
        float v1 = fmaxf(acc1[nt][1] + bv[1], 0.f);
        float v2 = fmaxf(acc1[nt][2] + bv[2], 0.f);
        float v3 = fmaxf(acc1[nt][3] + bv[3], 0.f);
        x1r[2 * nt]     = (unsigned int)f2bf(v0) | ((unsigned int)f2bf(v1) << 16);
        x1r[2 * nt + 1] = (unsigned int)f2bf(v2) | ((unsigned int)f2bf(v3) << 16);
    }
    // build all layer-2 A-frags once (reused by both column halves); x1r dies after
    bf16x8 a2f[8];
#pragma unroll
    for (int kt = 0; kt < 8; kt++) a2f[kt] = gather_afrag(x1r, kt, q, fr);

    // ---- layer 2: K=256 (8 kt), N=512 as two sequential 256-col halves ----
    unsigned int x2r[64];
#pragma unroll
    for (int nh = 0; nh < 2; nh++) {
        f32x4 acc2[16] = {};
#pragma unroll
        for (int kt = 0; kt < 8; kt++) {
            const int buf = (nh * 8 + kt) & 1;
            if (kt < 7)       stage_chunk(W2t, H1, nh * 16, kt + 1, buf ^ 1);
            else if (nh == 0) stage_chunk(W2t, H1, 16, 0, buf ^ 1);
            else              stage_chunk(Wgt, HIDDEN, 0, 0, buf ^ 1);   // layer-3 kt0
#pragma unroll
            for (int f = 0; f < 16; f++)
                acc2[f] = __builtin_amdgcn_mfma_f32_16x16x32_bf16(ldw(buf, f), a2f[kt], acc2[f], 0, 0, 0);
            __syncthreads();
        }
#pragma unroll
        for (int f = 0; f < 16; f++) {
            const int nt2 = nh * 16 + f;
            const f32x4 bv = *(const f32x4*)(b2 + nt2 * 16 + q * 4);
            float v0 = fmaxf(acc2[f][0] + bv[0], 0.f);
            float v1 = fmaxf(acc2[f][1] + bv[1], 0.f);
            float v2 = fmaxf(acc2[f][2] + bv[2], 0.f);
            float v3 = fmaxf(acc2[f][3] + bv[3], 0.f);
            x2r[2 * nt2]     = (unsigned int)f2bf(v0) | ((unsigned int)f2bf(v1) << 16);
            x2r[2 * nt2 + 1] = (unsigned int)f2bf(v2) | ((unsigned int)f2bf(v3) << 16);
        }
    }

    // ---- layer 3: K=512 (16 kt), N=256; A-frags shuffled from x2r on the fly ----
    f32x4 acc3[16] = {};
#pragma unroll
    for (int kt = 0; kt < 16; kt++) {
        const int buf = kt & 1;
        if (kt < 15) stage_chunk(Wgt, HIDDEN, 0, kt + 1, buf ^ 1);
        bf16x8 af = gather_afrag(x2r, kt, q, fr);
#pragma unroll
        for (int f = 0; f < 16; f++)
            acc3[f] = __builtin_amdgcn_mfma_f32_16x16x32_bf16(ldw(buf, f), af, acc3[f], 0, 0, 0);
        __syncthreads();
    }

    // ---- epilogue: hb store + fused attention dots (cols 0..255 = 4 heads x 64) ----
    float vs0 = 0.f, vs1 = 0.f, vs2 = 0.f, vs3 = 0.f;
    float vd0 = 0.f, vd1 = 0.f, vd2 = 0.f, vd3 = 0.f;
#pragma unroll
    for (int nt = 0; nt < 16; nt++) {
        const int col = nt * 16 + q * 4;
        const f32x4 x = acc3[nt];
        const f32x4 as = *(const f32x4*)(att_src + col);
        const f32x4 ad = *(const f32x4*)(att_dst + col);
        u16x4 p = { f2bf(x[0]), f2bf(x[1]), f2bf(x[2]), f2bf(x[3]) };
        *(u16x4*)(hb + (size_t)row * (HEADS * OUT_D) + col) = p;
        float ds = x[0] * as[0] + x[1] * as[1] + x[2] * as[2] + x[3] * as[3];
        float dd = x[0] * ad[0] + x[1] * ad[1] + x[2] * ad[2] + x[3] * ad[3];
        const int h = nt >> 2;
        if (h == 0) { vs0 += ds; vd0 += dd; }
        else if (h == 1) { vs1 += ds; vd1 += dd; }
        else if (h == 2) { vs2 += ds; vd2 += dd; }
        else { vs3 += ds; vd3 += dd; }
    }
#pragma unroll
    for (int off = 16; off <= 32; off <<= 1) {
        vs0 += __shfl_xor(vs0, off, 64); vs1 += __shfl_xor(vs1, off, 64);
        vs2 += __shfl_xor(vs2, off, 64); vs3 += __shfl_xor(vs3, off, 64);
        vd0 += __shfl_xor(vd0, off, 64); vd1 += __shfl_xor(vd1, off, 64);
        vd2 += __shfl_xor(vd2, off, 64); vd3 += __shfl_xor(vd3, off, 64);
    }
    if (q == 0 && row < N_NODES) {
        f32x4 s = { vs0, vs1, vs2, vs3 };
        f32x4 d = { vd0, vd1, vd2, vd3 };
        *(f32x4*)(a_src + row * HEADS) = s;
        *(f32x4*)(a_dst + row * HEADS) = d;
    }
}

// ---------------- CSR build ----------------
__global__ __launch_bounds__(256) void scan_a(const int* __restrict__ deg,
                                              int* __restrict__ t, int* __restrict__ bsum) {
    int i = blockIdx.x * 256 + threadIdx.x;
    int lane = threadIdx.x & 63, wave = threadIdx.x >> 6;
    int v = (i < N_NODES) ? deg[i] + 1 : 0;
    int s = v;
#pragma unroll
    for (int off = 1; off < 64; off <<= 1) {
        int u = __shfl_up(s, off, 64);
        if (lane >= off) s += u;
    }
    __shared__ int wsum[4];
    if (lane == 63) wsum[wave] = s;
    __syncthreads();
    int woff = 0;
    for (int w = 0; w < wave; w++) woff += wsum[w];
    s += woff;
    if (i < N_NODES) t[i] = s;
    if (threadIdx.x == 255) bsum[blockIdx.x] = s;
}

__global__ __launch_bounds__(256) void scan_c(const int* __restrict__ t, const int* __restrict__ deg,
                                              const int* __restrict__ bsum,
                                              int* __restrict__ row_start, int* __restrict__ cursor) {
    __shared__ int boff_s;
    if (threadIdx.x < 64) {
        int s = 0;
        for (int i = threadIdx.x; i < blockIdx.x; i += 64) s += bsum[i];
#pragma unroll
        for (int off = 32; off > 0; off >>= 1) s += __shfl_xor(s, off, 64);
        if (threadIdx.x == 0) boff_s = s;
    }
    __syncthreads();
    int i = blockIdx.x * 256 + threadIdx.x;
    if (i >= N_NODES) return;
    int incl = t[i] + boff_s;
    int start = incl - (deg[i] + 1);
    row_start[i] = start;
    cursor[i] = start;
}

// ---------------- scatter edges + precompute leaky-relu'd logits ----------------
__global__ void scatter_logits(const int* __restrict__ ei, int* __restrict__ cursor,
                               const int* __restrict__ row_start, const int* __restrict__ deg,
                               const float* __restrict__ a_src, const float* __restrict__ a_dst,
                               int* __restrict__ adj, float* __restrict__ elog) {
    int t = blockIdx.x * blockDim.x + threadIdx.x;
    if (t >= E_EDGES + N_NODES) return;
    int s, d, slot;
    if (t < E_EDGES) {
        s = ei[t]; d = ei[E_EDGES + t];
        slot = atomicAdd(&cursor[d], 1);
    } else {
        s = d = t - E_EDGES;
        slot = row_start[d] + deg[d];
    }
    adj[slot] = s;
    f32x4 as = *(const f32x4*)(a_src + s * HEADS);
    f32x4 ad = *(const f32x4*)(a_dst + d * HEADS);
    f32x4 o;
#pragma unroll
    for (int h = 0; h < HEADS; h++) {
        float v = as[h] + ad[h];
        o[h] = (v > 0.f) ? v : NEG_SLOPE * v;
    }
    *(f32x4*)(elog + (size_t)slot * HEADS) = o;
}

// ---------------- fused segment-softmax + gather-aggregate: one wave per node ----------------
__global__ __launch_bounds__(256) void fused_gat(const int* __restrict__ adj,
                                                 const int* __restrict__ row_start,
                                                 const int* __restrict__ deg,
                                                 const float* __restrict__ elog,
                                                 const unsigned short* __restrict__ hb,
                                                 const float* __restrict__ bias_g,
                                                 float* __restrict__ out) {
    const int wave = threadIdx.x >> 6, lane = threadIdx.x & 63;
    const int d = blockIdx.x * 4 + wave;      // N_NODES % 4 == 0
    const int base = row_start[d];
    const int cnt = deg[d] + 1;
    const int h = lane >> 4, j = lane & 15;

    __shared__ float lw[4][HEADS][32];
    __shared__ int   si[4][32];

    float mx = -1e30f;
    for (int e = j; e < cnt; e += 16) {
        float v = elog[(size_t)(base + e) * HEADS + h];
        if (e < 32) {
            lw[wave][h][e] = v;
            if (h == 0) si[wave][e] = adj[base + e];
        }
        mx = fmaxf(mx, v);
    }
#pragma unroll
    for (int off = 1; off < 16; off <<= 1) mx = fmaxf(mx, __shfl_xor(mx, off, 64));

    float sm = 0.f;
    for (int e = j; e < cnt; e += 16) {
        float v = (e < 32) ? lw[wave][h][e] : elog[(size_t)(base + e) * HEADS + h];
        sm += __expf(v - mx);
    }
#pragma unroll
    for (int off = 1; off < 16; off <<= 1) sm += __shfl_xor(sm, off, 64);
    const float inv = 1.f / (sm + 1e-16f);

    for (int e = j; e < cnt && e < 32; e += 16)
        lw[wave][h][e] = __expf(lw[wave][h][e] - mx) * inv;

    // phase 2: weighted gather, 8 loads in flight
    float a0 = 0.f, a1 = 0.f, a2 = 0.f, a3 = 0.f;
    const int lim = cnt < 32 ? cnt : 32;
    const unsigned short* hp = hb + h * OUT_D + j * 4;
    int e = 0;
    for (; e + 7 < lim; e += 8) {
        int   sx[8]; float wx[8]; u16x4 gx[8];
#pragma unroll
        for (int u = 0; u < 8; u++) { sx[u] = si[wave][e + u]; wx[u] = lw[wave][h][e + u]; }
#pragma unroll
        for (int u = 0; u < 8; u++) gx[u] = *(const u16x4*)(hp + (size_t)sx[u] * (HEADS * OUT_D));
#pragma unroll
        for (int u = 0; u < 8; u++) {
            a0 += wx[u] * bf2f(gx[u][0]); a1 += wx[u] * bf2f(gx[u][1]);
            a2 += wx[u] * bf2f(gx[u][2]); a3 += wx[u] * bf2f(gx[u][3]);
        }
    }
    for (; e + 3 < lim; e += 4) {
        int   sx[4]; float wx[4]; u16x4 gx[4];
#pragma unroll
        for (int u = 0; u < 4; u++) { sx[u] = si[wave][e + u]; wx[u] = lw[wave][h][e + u]; }
#pragma unroll
        for (int u = 0; u < 4; u++) gx[u] = *(const u16x4*)(hp + (size_t)sx[u] * (HEADS * OUT_D));
#pragma unroll
        for (int u = 0; u < 4; u++) {
            a0 += wx[u] * bf2f(gx[u][0]); a1 += wx[u] * bf2f(gx[u][1]);
            a2 += wx[u] * bf2f(gx[u][2]); a3 += wx[u] * bf2f(gx[u][3]);
        }
    }
    for (; e < lim; e++) {
        int s = si[wave][e];
        float w = lw[wave][h][e];
        u16x4 g = *(const u16x4*)(hp + (size_t)s * (HEADS * OUT_D));
        a0 += w * bf2f(g[0]); a1 += w * bf2f(g[1]);
        a2 += w * bf2f(g[2]); a3 += w * bf2f(g[3]);
    }
    for (int e2 = 32; e2 < cnt; e2++) {   // rare (deg >= 32)
        int s = adj[base + e2];
        float w = __expf(elog[(size_t)(base + e2) * HEADS + h] - mx) * inv;
        u16x4 g = *(const u16x4*)(hp + (size_t)s * (HEADS * OUT_D));
        a0 += w * bf2f(g[0]); a1 += w * bf2f(g[1]);
        a2 += w * bf2f(g[2]); a3 += w * bf2f(g[3]);
    }

    a0 += __shfl_xor(a0, 16, 64); a0 += __shfl_xor(a0, 32, 64);
    a1 += __shfl_xor(a1, 16, 64); a1 += __shfl_xor(a1, 32, 64);
    a2 += __shfl_xor(a2, 16, 64); a2 += __shfl_xor(a2, 32, 64);
    a3 += __shfl_xor(a3, 16, 64); a3 += __shfl_xor(a3, 32, 64);
    if (lane < 16) {
        f32x4 bg = *(const f32x4*)(bias_g + lane * 4);
        f32x4 r = { 0.25f * a0 + bg[0], 0.25f * a1 + bg[1],
                    0.25f * a2 + bg[2], 0.25f * a3 + bg[3] };
        *(f32x4*)(out + (size_t)d * OUT_D + lane * 4) = r;
    }
}

extern "C" void kernel_launch(void* const* d_in, const int* in_sizes, int n_in,
                              void* d_out, int out_size, void* d_ws, size_t ws_size,
                              hipStream_t stream) {
    const float* z       = (const float*)d_in[0];
    const float* W1      = (const float*)d_in[1];
    const float* b1      = (const float*)d_in[2];
    const float* W2      = (const float*)d_in[3];
    const float* b2      = (const float*)d_in[4];
    const float* Wg      = (const float*)d_in[5];
    const float* att_src = (const float*)d_in[6];
    const float* att_dst = (const float*)d_in[7];
    const float* bias_g  = (const float*)d_in[8];
    const int*   ei      = (const int*)d_in[9];
    float* out = (float*)d_out;

    char* ws = (char*)d_ws;
    size_t off = 0;
    auto carve = [&](size_t bytes) { void* p = ws + off; off += (bytes + 255) & ~(size_t)255; return p; };

    unsigned short* W1t = (unsigned short*)carve((size_t)H1 * LATENT * 2);
    unsigned short* W2t = (unsigned short*)carve((size_t)HIDDEN * H1 * 2);
    unsigned short* Wgt = (unsigned short*)carve((size_t)(HEADS * OUT_D) * HIDDEN * 2);
    unsigned short* hb  = (unsigned short*)carve((size_t)MPAD * HEADS * OUT_D * 2);
    float* a_src = (float*)carve((size_t)N_NODES * HEADS * 4);
    float* a_dst = (float*)carve((size_t)N_NODES * HEADS * 4);
    int* deg       = (int*)carve((size_t)N_NODES * 4);
    int* tmp_scan  = (int*)carve((size_t)N_NODES * 4);
    int* bsum      = (int*)carve((size_t)NBLK_SCAN * 4);
    int* row_start = (int*)carve((size_t)N_NODES * 4);
    int* cursor    = (int*)carve((size_t)N_NODES * 4);
    int* adj       = (int*)carve((size_t)(E_EDGES + N_NODES) * 4);
    float* elog    = (float*)carve((size_t)(E_EDGES + N_NODES) * HEADS * 4);

    hipMemsetAsync(deg, 0, (size_t)N_NODES * 4, stream);

    prep_kernel<<<(WTOT + E_EDGES + 255) / 256, 256, 0, stream>>>(
        W1, W2, Wg, ei, W1t, W2t, Wgt, deg);

    scan_a<<<NBLK_SCAN, 256, 0, stream>>>(deg, tmp_scan, bsum);
    scan_c<<<NBLK_SCAN, 256, 0, stream>>>(tmp_scan, deg, bsum, row_start, cursor);

    // fused MLP v2: 314 blocks x 256 threads, LDS-staged weights, register activations
    mlp_all_kernel<<<MPAD / TMB, 256, 0, stream>>>(
        z, W1t, W2t, Wgt, b1, b2, att_src, att_dst, hb, a_src, a_dst);

    scatter_logits<<<(E_EDGES + N_NODES + 255) / 256, 256, 0, stream>>>(
        ei, cursor, row_start, deg, a_src, a_dst, adj, elog);

    fused_gat<<<N_NODES / 4, 256, 0, stream>>>(adj, row_start, deg, elog, hb, bias_g, out);
}

// Round 14
// 211.474 us; speedup vs baseline: 1.0902x; 1.0902x over previous
//
#include <hip/hip_runtime.h>
#include <hip/hip_bf16.h>

#define N_NODES 20000
#define MPAD    20096
#define E_EDGES 400000
#define LATENT 128
#define H1 256
#define HIDDEN 512
#define OUT_D 64
#define HEADS 4
#define NEG_SLOPE 0.2f
#define NBLK_SCAN ((N_NODES + 255) / 256)   // 79

typedef __attribute__((ext_vector_type(8))) __bf16 bf16x8;
typedef __attribute__((ext_vector_type(4))) float f32x4;
typedef __attribute__((ext_vector_type(4))) unsigned short u16x4;

__device__ __forceinline__ unsigned short f2bf(float f) {
    union { float f; unsigned int u; } v; v.f = f;
    unsigned int r = v.u + 0x7fffu + ((v.u >> 16) & 1u);  // RNE
    return (unsigned short)(r >> 16);
}
__device__ __forceinline__ float bf2f(unsigned short u) {
    union { unsigned int u; float f; } v; v.u = ((unsigned int)u) << 16;
    return v.f;
}

// ---------------- weights transpose-convert + degree histogram (ONE launch) ----------------
#define SEG1 (LATENT * H1)
#define SEG2 (H1 * HIDDEN)
#define SEG3 (HIDDEN * HEADS * OUT_D)
#define WTOT (SEG1 + SEG2 + SEG3)
__global__ __launch_bounds__(256)
void prep_kernel(const float* __restrict__ W1, const float* __restrict__ W2,
                 const float* __restrict__ Wg, const int* __restrict__ ei,
                 unsigned short* __restrict__ W1t, unsigned short* __restrict__ W2t,
                 unsigned short* __restrict__ Wgt, int* __restrict__ deg) {
    int t = blockIdx.x * blockDim.x + threadIdx.x;
    if (t < SEG1) { int k = t >> 8, n = t & 255; W1t[n * LATENT + k] = f2bf(W1[t]); return; }
    t -= SEG1;
    if (t < SEG2) { int k = t >> 9, n = t & 511; W2t[n * H1 + k] = f2bf(W2[t]); return; }
    t -= SEG2;
    if (t < SEG3) { int k = t >> 8, n = t & 255; Wgt[n * HIDDEN + k] = f2bf(Wg[t]); return; }
    t -= SEG3;
    if (t < E_EDGES) atomicAdd(&deg[ei[E_EDGES + t]], 1);
}

// ---------------- fully fused MLP + att coefs (R12 champion — 60.6 us measured) ----------------
// TM=32 rows/block -> 628 blocks, 256 threads. x1/x2 in LDS; zbf ALIASES x2s.
// NOTE (R8-R13): all pipelining attempts failed — register dbuf gets sunk (VGPR 88/44/96)
// or spills (R10), LDS-DMA dbuf pays a vmcnt drain at every per-kt barrier (R13: 75 us).
// ~60 us is this MLP's practical floor: K per layer is too small for pipeline ramp.
#define TM 32
#define ZPITCH 136
#define XPITCH 264
#define X2PITCH 520
__global__ __launch_bounds__(256)
void mlp_all_kernel(const float* __restrict__ z,
                    const unsigned short* __restrict__ W1t,
                    const unsigned short* __restrict__ W2t,
                    const unsigned short* __restrict__ Wgt,
                    const float* __restrict__ b1, const float* __restrict__ b2,
                    const float* __restrict__ att_src, const float* __restrict__ att_dst,
                    unsigned short* __restrict__ hb,
                    float* __restrict__ a_src, float* __restrict__ a_dst) {
    __shared__ unsigned short x2s[TM * X2PITCH];   // 33.3 KB; first 8.7 KB aliased as zbf
    __shared__ unsigned short x1s[TM * XPITCH];    // 16.9 KB (50.2 KB total)
    unsigned short* zbf = x2s;
    const int tid = threadIdx.x;
    const int wave = tid >> 6, lane = tid & 63;
    const int m0 = blockIdx.x * TM;
    const int fr = lane & 15, q = lane >> 4;

#define LDW1(kt, t) (*(const bf16x8*)(W1t + (size_t)(nb1 + (t) * 16 + fr) * LATENT + (kt) * 32 + q * 8))
#define LDW2(kt, t) (*(const bf16x8*)(W2t + (size_t)(nb2 + (t) * 16 + fr) * H1     + (kt) * 32 + q * 8))
#define LDW3(kt, t) (*(const bf16x8*)(Wgt + (size_t)(nb3 + (t) * 16 + fr) * HIDDEN + (kt) * 32 + q * 8))

    const int nb1 = wave * 64;
    const int nb2 = wave * 128;
    const int head = wave;
    const int nb3 = wave * 64;

    bf16x8 w1a[4], w1b[4];
#pragma unroll
    for (int t = 0; t < 4; t++) w1a[t] = LDW1(0, t);

    {
        const int r = tid >> 3, c0 = (tid & 7) * 16;
        const int zrow = min(m0 + r, N_NODES - 1);
        const float* zp = z + (size_t)zrow * LATENT + c0;
#pragma unroll
        for (int i = 0; i < 4; i++) {
            f32x4 v = *(const f32x4*)(zp + i * 4);
            u16x4 p = { f2bf(v[0]), f2bf(v[1]), f2bf(v[2]), f2bf(v[3]) };
            *(u16x4*)(zbf + r * ZPITCH + c0 + i * 4) = p;
        }
    }
    __syncthreads();

    // ---- layer 1 ----
    f32x4 acc1[2][4] = {};
#pragma unroll
    for (int kt = 0; kt < 4; kt++) {
        bf16x8* wc = (kt & 1) ? w1b : w1a;
        bf16x8* wn = (kt & 1) ? w1a : w1b;
        if (kt < 3) {
#pragma unroll
            for (int t = 0; t < 4; t++) wn[t] = LDW1(kt + 1, t);
        }
        bf16x8 af[2];
#pragma unroll
        for (int t = 0; t < 2; t++)
            af[t] = *(const bf16x8*)(zbf + (t * 16 + fr) * ZPITCH + kt * 32 + q * 8);
#pragma unroll
        for (int mt = 0; mt < 2; mt++)
#pragma unroll
            for (int nt = 0; nt < 4; nt++)
                acc1[mt][nt] = __builtin_amdgcn_mfma_f32_16x16x32_bf16(
                    wc[nt], af[mt], acc1[mt][nt], 0, 0, 0);
    }

    bf16x8 w2a[8], w2b[8];
#pragma unroll
    for (int t = 0; t < 8; t++) w2a[t] = LDW2(0, t);

#pragma unroll
    for (int nt = 0; nt < 4; nt++) {
        const int n = nb1 + nt * 16 + q * 4;
        const f32x4 bv = *(const f32x4*)(b1 + n);
#pragma unroll
        for (int mt = 0; mt < 2; mt++) {
            u16x4 p;
#pragma unroll
            for (int r = 0; r < 4; r++) p[r] = f2bf(fmaxf(acc1[mt][nt][r] + bv[r], 0.f));
            *(u16x4*)(x1s + (mt * 16 + fr) * XPITCH + n) = p;
        }
    }
    __syncthreads();

    // ---- layer 2 ----
    f32x4 acc2[2][8] = {};
#pragma unroll
    for (int kt = 0; kt < 8; kt++) {
        bf16x8* wc = (kt & 1) ? w2b : w2a;
        bf16x8* wn = (kt & 1) ? w2a : w2b;
        if (kt < 7) {
#pragma unroll
            for (int t = 0; t < 8; t++) wn[t] = LDW2(kt + 1, t);
        }
        bf16x8 af[2];
#pragma unroll
        for (int t = 0; t < 2; t++)
            af[t] = *(const bf16x8*)(x1s + (t * 16 + fr) * XPITCH + kt * 32 + q * 8);
#pragma unroll
        for (int mt = 0; mt < 2; mt++)
#pragma unroll
            for (int nt = 0; nt < 8; nt++)
                acc2[mt][nt] = __builtin_amdgcn_mfma_f32_16x16x32_bf16(
                    wc[nt], af[mt], acc2[mt][nt], 0, 0, 0);
    }

    bf16x8 w3a[4], w3b[4];
#pragma unroll
    for (int t = 0; t < 4; t++) w3a[t] = LDW3(0, t);

#pragma unroll
    for (int nt = 0; nt < 8; nt++) {
        const int n = nb2 + nt * 16 + q * 4;
        const f32x4 bv = *(const f32x4*)(b2 + n);
#pragma unroll
        for (int mt = 0; mt < 2; mt++) {
            u16x4 p;
#pragma unroll
            for (int r = 0; r < 4; r++) p[r] = f2bf(fmaxf(acc2[mt][nt][r] + bv[r], 0.f));
            *(u16x4*)(x2s + (mt * 16 + fr) * X2PITCH + n) = p;
        }
    }
    __syncthreads();

    // ---- layer 3 + att epilogue ----
    f32x4 acc3[2][4] = {};
#pragma unroll
    for (int kt = 0; kt < 16; kt++) {
        bf16x8* wc = (kt & 1) ? w3b : w3a;
        bf16x8* wn = (kt & 1) ? w3a : w3b;
        if (kt < 15) {
#pragma unroll
            for (int t = 0; t < 4; t++) wn[t] = LDW3(kt + 1, t);
        }
        bf16x8 af[2];
#pragma unroll
        for (int t = 0; t < 2; t++)
            af[t] = *(const bf16x8*)(x2s + (t * 16 + fr) * X2PITCH + kt * 32 + q * 8);
#pragma unroll
        for (int mt = 0; mt < 2; mt++)
#pragma unroll
            for (int nt = 0; nt < 4; nt++)
                acc3[mt][nt] = __builtin_amdgcn_mfma_f32_16x16x32_bf16(
                    wc[nt], af[mt], acc3[mt][nt], 0, 0, 0);
    }

    {
        f32x4 asv[4], adv[4];
#pragma unroll
        for (int nt = 0; nt < 4; nt++) {
            asv[nt] = *(const f32x4*)(att_src + head * OUT_D + nt * 16 + q * 4);
            adv[nt] = *(const f32x4*)(att_dst + head * OUT_D + nt * 16 + q * 4);
        }
#pragma unroll
        for (int mt = 0; mt < 2; mt++) {
            const int row = m0 + mt * 16 + fr;
            float vs = 0.f, vd = 0.f;
#pragma unroll
            for (int nt = 0; nt < 4; nt++) {
                u16x4 p;
#pragma unroll
                for (int r = 0; r < 4; r++) {
                    float x = acc3[mt][nt][r];
                    p[r] = f2bf(x);
                    vs += x * asv[nt][r];
                    vd += x * adv[nt][r];
                }
                *(u16x4*)(hb + (size_t)row * (HEADS * OUT_D) + head * OUT_D + nt * 16 + q * 4) = p;
            }
            vs += __shfl_xor(vs, 16, 64); vs += __shfl_xor(vs, 32, 64);
            vd += __shfl_xor(vd, 16, 64); vd += __shfl_xor(vd, 32, 64);
            if (q == 0 && row < N_NODES) {
                a_src[row * HEADS + head] = vs;
                a_dst[row * HEADS + head] = vd;
            }
        }
    }
#undef LDW1
#undef LDW2
#undef LDW3
}

// ---------------- CSR build ----------------
__global__ __launch_bounds__(256) void scan_a(const int* __restrict__ deg,
                                              int* __restrict__ t, int* __restrict__ bsum) {
    int i = blockIdx.x * 256 + threadIdx.x;
    int lane = threadIdx.x & 63, wave = threadIdx.x >> 6;
    int v = (i < N_NODES) ? deg[i] + 1 : 0;
    int s = v;
#pragma unroll
    for (int off = 1; off < 64; off <<= 1) {
        int u = __shfl_up(s, off, 64);
        if (lane >= off) s += u;
    }
    __shared__ int wsum[4];
    if (lane == 63) wsum[wave] = s;
    __syncthreads();
    int woff = 0;
    for (int w = 0; w < wave; w++) woff += wsum[w];
    s += woff;
    if (i < N_NODES) t[i] = s;
    if (threadIdx.x == 255) bsum[blockIdx.x] = s;
}

__global__ __launch_bounds__(256) void scan_c(const int* __restrict__ t, const int* __restrict__ deg,
                                              const int* __restrict__ bsum,
                                              int* __restrict__ row_start, int* __restrict__ cursor) {
    __shared__ int boff_s;
    if (threadIdx.x < 64) {
        int s = 0;
        for (int i = threadIdx.x; i < blockIdx.x; i += 64) s += bsum[i];
#pragma unroll
        for (int off = 32; off > 0; off >>= 1) s += __shfl_xor(s, off, 64);
        if (threadIdx.x == 0) boff_s = s;
    }
    __syncthreads();
    int i = blockIdx.x * 256 + threadIdx.x;
    if (i >= N_NODES) return;
    int incl = t[i] + boff_s;
    int start = incl - (deg[i] + 1);
    row_start[i] = start;
    cursor[i] = start;
}

// ---------------- scatter edges + store exp(leaky(logit)) per head ----------------
// Max-subtraction is a mathematical no-op on softmax weights; logits here are O(1)
// (clamped at 60 for overflow safety), so exp() is computed ONCE here and fused_gat's
// softmax becomes a single sum pass. Self-loop slots covered (t >= E).
__global__ void scatter_logits(const int* __restrict__ ei, int* __restrict__ cursor,
                               const int* __restrict__ row_start, const int* __restrict__ deg,
                               const float* __restrict__ a_src, const float* __restrict__ a_dst,
                               int* __restrict__ adj, float* __restrict__ eex) {
    int t = blockIdx.x * blockDim.x + threadIdx.x;
    if (t >= E_EDGES + N_NODES) return;
    int s, d, slot;
    if (t < E_EDGES) {
        s = ei[t]; d = ei[E_EDGES + t];
        slot = atomicAdd(&cursor[d], 1);
    } else {
        s = d = t - E_EDGES;
        slot = row_start[d] + deg[d];
    }
    adj[slot] = s;
    f32x4 as = *(const f32x4*)(a_src + s * HEADS);
    f32x4 ad = *(const f32x4*)(a_dst + d * HEADS);
    f32x4 o;
#pragma unroll
    for (int h = 0; h < HEADS; h++) {
        float v = as[h] + ad[h];
        v = (v > 0.f) ? v : NEG_SLOPE * v;
        o[h] = __expf(fminf(v, 60.f));
    }
    *(f32x4*)(eex + (size_t)slot * HEADS) = o;
}

// ---------------- fused segment-softmax + gather-aggregate: one wave per node ----------------
// Phase 1 is now a SINGLE contiguous pass over eex (sum only — no max pass, no exp,
// no LDS rewrite); inv is folded into the phase-2 weight multiply.
__global__ __launch_bounds__(256) void fused_gat(const int* __restrict__ adj,
                                                 const int* __restrict__ row_start,
                                                 const int* __restrict__ deg,
                                                 const float* __restrict__ eex,
                                                 const unsigned short* __restrict__ hb,
                                                 const float* __restrict__ bias_g,
                                                 float* __restrict__ out) {
    const int wave = threadIdx.x >> 6, lane = threadIdx.x & 63;
    const int d = blockIdx.x * 4 + wave;      // N_NODES % 4 == 0
    const int base = row_start[d];
    const int cnt = deg[d] + 1;
    const int h = lane >> 4, j = lane & 15;

    __shared__ float lw[4][HEADS][32];
    __shared__ int   si[4][32];

    // single pass: stash ex + sum
    float sm = 0.f;
    for (int e = j; e < cnt; e += 16) {
        float ex = eex[(size_t)(base + e) * HEADS + h];
        if (e < 32) {
            lw[wave][h][e] = ex;
            if (h == 0) si[wave][e] = adj[base + e];
        }
        sm += ex;
    }
#pragma unroll
    for (int off = 1; off < 16; off <<= 1) sm += __shfl_xor(sm, off, 64);
    const float inv = 1.f / (sm + 1e-16f);

    // phase 2: weighted gather, 8 loads in flight; inv folded into the weight
    float a0 = 0.f, a1 = 0.f, a2 = 0.f, a3 = 0.f;
    const int lim = cnt < 32 ? cnt : 32;
    const unsigned short* hp = hb + h * OUT_D + j * 4;
    int e = 0;
    for (; e + 7 < lim; e += 8) {
        int   sx[8]; float wx[8]; u16x4 gx[8];
#pragma unroll
        for (int u = 0; u < 8; u++) { sx[u] = si[wave][e + u]; wx[u] = lw[wave][h][e + u]; }
#pragma unroll
        for (int u = 0; u < 8; u++) gx[u] = *(const u16x4*)(hp + (size_t)sx[u] * (HEADS * OUT_D));
#pragma unroll
        for (int u = 0; u < 8; u++) {
            a0 += wx[u] * bf2f(gx[u][0]); a1 += wx[u] * bf2f(gx[u][1]);
            a2 += wx[u] * bf2f(gx[u][2]); a3 += wx[u] * bf2f(gx[u][3]);
        }
    }
    for (; e + 3 < lim; e += 4) {
        int   sx[4]; float wx[4]; u16x4 gx[4];
#pragma unroll
        for (int u = 0; u < 4; u++) { sx[u] = si[wave][e + u]; wx[u] = lw[wave][h][e + u]; }
#pragma unroll
        for (int u = 0; u < 4; u++) gx[u] = *(const u16x4*)(hp + (size_t)sx[u] * (HEADS * OUT_D));
#pragma unroll
        for (int u = 0; u < 4; u++) {
            a0 += wx[u] * bf2f(gx[u][0]); a1 += wx[u] * bf2f(gx[u][1]);
            a2 += wx[u] * bf2f(gx[u][2]); a3 += wx[u] * bf2f(gx[u][3]);
        }
    }
    for (; e < lim; e++) {
        int s = si[wave][e];
        float w = lw[wave][h][e];
        u16x4 g = *(const u16x4*)(hp + (size_t)s * (HEADS * OUT_D));
        a0 += w * bf2f(g[0]); a1 += w * bf2f(g[1]);
        a2 += w * bf2f(g[2]); a3 += w * bf2f(g[3]);
    }
    for (int e2 = 32; e2 < cnt; e2++) {   // rare (deg >= 32): re-read eex, no exp needed
        int s = adj[base + e2];
        float w = eex[(size_t)(base + e2) * HEADS + h];
        u16x4 g = *(const u16x4*)(hp + (size_t)s * (HEADS * OUT_D));
        a0 += w * bf2f(g[0]); a1 += w * bf2f(g[1]);
        a2 += w * bf2f(g[2]); a3 += w * bf2f(g[3]);
    }
    a0 *= inv; a1 *= inv; a2 *= inv; a3 *= inv;

    a0 += __shfl_xor(a0, 16, 64); a0 += __shfl_xor(a0, 32, 64);
    a1 += __shfl_xor(a1, 16, 64); a1 += __shfl_xor(a1, 32, 64);
    a2 += __shfl_xor(a2, 16, 64); a2 += __shfl_xor(a2, 32, 64);
    a3 += __shfl_xor(a3, 16, 64); a3 += __shfl_xor(a3, 32, 64);
    if (lane < 16) {
        f32x4 bg = *(const f32x4*)(bias_g + lane * 4);
        f32x4 r = { 0.25f * a0 + bg[0], 0.25f * a1 + bg[1],
                    0.25f * a2 + bg[2], 0.25f * a3 + bg[3] };
        *(f32x4*)(out + (size_t)d * OUT_D + lane * 4) = r;
    }
}

extern "C" void kernel_launch(void* const* d_in, const int* in_sizes, int n_in,
                              void* d_out, int out_size, void* d_ws, size_t ws_size,
                              hipStream_t stream) {
    const float* z       = (const float*)d_in[0];
    const float* W1      = (const float*)d_in[1];
    const float* b1      = (const float*)d_in[2];
    const float* W2      = (const float*)d_in[3];
    const float* b2      = (const float*)d_in[4];
    const float* Wg      = (const float*)d_in[5];
    const float* att_src = (const float*)d_in[6];
    const float* att_dst = (const float*)d_in[7];
    const float* bias_g  = (const float*)d_in[8];
    const int*   ei      = (const int*)d_in[9];
    float* out = (float*)d_out;

    char* ws = (char*)d_ws;
    size_t off = 0;
    auto carve = [&](size_t bytes) { void* p = ws + off; off += (bytes + 255) & ~(size_t)255; return p; };

    unsigned short* W1t = (unsigned short*)carve((size_t)H1 * LATENT * 2);
    unsigned short* W2t = (unsigned short*)carve((size_t)HIDDEN * H1 * 2);
    unsigned short* Wgt = (unsigned short*)carve((size_t)(HEADS * OUT_D) * HIDDEN * 2);
    unsigned short* hb  = (unsigned short*)carve((size_t)MPAD * HEADS * OUT_D * 2);
    float* a_src = (float*)carve((size_t)N_NODES * HEADS * 4);
    float* a_dst = (float*)carve((size_t)N_NODES * HEADS * 4);
    int* deg       = (int*)carve((size_t)N_NODES * 4);
    int* tmp_scan  = (int*)carve((size_t)N_NODES * 4);
    int* bsum      = (int*)carve((size_t)NBLK_SCAN * 4);
    int* row_start = (int*)carve((size_t)N_NODES * 4);
    int* cursor    = (int*)carve((size_t)N_NODES * 4);
    int* adj       = (int*)carve((size_t)(E_EDGES + N_NODES) * 4);
    float* eex     = (float*)carve((size_t)(E_EDGES + N_NODES) * HEADS * 4);

    hipMemsetAsync(deg, 0, (size_t)N_NODES * 4, stream);

    prep_kernel<<<(WTOT + E_EDGES + 255) / 256, 256, 0, stream>>>(
        W1, W2, Wg, ei, W1t, W2t, Wgt, deg);

    scan_a<<<NBLK_SCAN, 256, 0, stream>>>(deg, tmp_scan, bsum);
    scan_c<<<NBLK_SCAN, 256, 0, stream>>>(tmp_scan, deg, bsum, row_start, cursor);

    // fused MLP (R12 champion config)
    mlp_all_kernel<<<MPAD / TM, 256, 0, stream>>>(
        z, W1t, W2t, Wgt, b1, b2, att_src, att_dst, hb, a_src, a_dst);

    scatter_logits<<<(E_EDGES + N_NODES + 255) / 256, 256, 0, stream>>>(
        ei, cursor, row_start, deg, a_src, a_dst, adj, eex);

    fused_gat<<<N_NODES / 4, 256, 0, stream>>>(adj, row_start, deg, eex, hb, bias_g, out);
}